// Round 3
// baseline (15715.642 us; speedup 1.0000x reference)
//
#include <hip/hip_runtime.h>

// Bidirectional (feature-reversed) 2-layer LSTM, persistent-wave design.
// 4 chains = (dir, layer) x 2 decoupled m-halves; each chain = 32 one-wave
// blocks. Weights resident in VGPRs (256 regs/wave f16).
//
// R3: self-tagged h exchange. h published as u64 = (tag<<32)|(2 x f16) with
// relaxed SYSTEM-scope atomics (sc0 sc1, coherent at MALL). Consumers poll
// the data words for tag==t: no drain->flag->detect->load chain (4 RTs -> ~1.5).
// Slot reuse (8 slots) guarded by 8 aggregated atomicAdd counters with 7-tick
// slack (off critical path). x@Wih MFMAs hoisted before the poll.

typedef _Float16 half8 __attribute__((ext_vector_type(8)));
typedef float f32x4 __attribute__((ext_vector_type(4)));
typedef unsigned long long u64;

#define B_ 32
#define S_ 2048
#define D_ 256
#define H_ 256
#define G_ 1024
#define NSLOT 8
#define OUT0 (B_*S_*2*H_)   /* 33554432 */

// hbufT: [chain][slot][row(32)][colpair(128)] u64; u64=(tag<<32)|(hOdd<<16)|hEven
#define ROWU 128
#define SLOTU (B_*ROWU)        /* 4096 */
#define CHAINU (NSLOT*SLOTU)   /* 32768 */

__device__ __forceinline__ float sigmoidf_(float v){ return 1.f/(1.f+__expf(-v)); }
__device__ __forceinline__ float tanhf_(float v){ return 2.f/(1.f+__expf(-2.f*v)) - 1.f; }

union H8U { half8 h; unsigned d[4]; };

// ws layout: [0,8192): 8 counters (64B stride); [8192, 8192+1MB): hbufT
__global__ __launch_bounds__(256) void lstm_prep(const float* __restrict__ enc_h,
                                                 int* __restrict__ flags,
                                                 u64* __restrict__ hbufT)
{
  int idx = blockIdx.x*blockDim.x + threadIdx.x;
  if (idx < 8)
    __hip_atomic_store(&flags[idx*16], 0, __ATOMIC_RELAXED, __HIP_MEMORY_SCOPE_SYSTEM);
  for (int i = idx; i < 4*SLOTU; i += gridDim.x*blockDim.x) {
    int chain = i >> 12;
    int r     = i & 4095;
    int row   = r >> 7;
    int cp    = r & 127;
    int dir   = chain >> 1;
    _Float16 e0 = (_Float16)enc_h[row*(2*H_) + dir*H_ + cp*2];
    _Float16 e1 = (_Float16)enc_h[row*(2*H_) + dir*H_ + cp*2 + 1];
    unsigned lo = (unsigned)__builtin_bit_cast(unsigned short, e0)
                | ((unsigned)__builtin_bit_cast(unsigned short, e1) << 16);
    u64 v = (u64)lo;   // tag 0
    __hip_atomic_store(&hbufT[(size_t)chain*CHAINU + (size_t)row*ROWU + cp], v,
                       __ATOMIC_RELAXED, __HIP_MEMORY_SCOPE_SYSTEM);
  }
}

__global__ __launch_bounds__(64,1) void lstm_main(
    const float* __restrict__ x,
    const float* __restrict__ enc_c,
    const float* __restrict__ Wih_f, const float* __restrict__ Whh_f,
    const float* __restrict__ bih_f, const float* __restrict__ bhh_f,
    const float* __restrict__ Wih_b, const float* __restrict__ Whh_b,
    const float* __restrict__ bih_b, const float* __restrict__ bhh_b,
    float* __restrict__ out,
    int* __restrict__ flags,
    u64* __restrict__ hbufT)
{
  const int bid   = blockIdx.x;   // 0..127
  const int chain = bid & 3;      // dir*2 + layer
  const int w     = bid >> 2;     // member 0..31
  const int dir   = chain >> 1;
  const int layer = chain & 1;
  const int m     = w & 1;        // batch 16-row half
  const int c0    = (w >> 1) << 4;// h-column base (16 cols)
  const int lane  = threadIdx.x;
  const int quad  = lane >> 4;
  const int lq    = lane & 15;

  const float* Wih = dir ? Wih_b : Wih_f;
  const float* Whh = dir ? Whh_b : Whh_f;
  const float* bih = dir ? bih_b : bih_f;
  const float* bhh = dir ? bhh_b : bhh_f;

  // resident B-fragments: bf[q][kk] (kk<8: Wih, kk>=8: Whh)
  half8 bf[4][16];
#pragma unroll
  for (int q = 0; q < 4; ++q) {
    const int n_g = q*256 + c0 + lq;
    const float* wihr = Wih + (size_t)layer*G_*256 + (size_t)n_g*256 + quad*8;
    const float* whhr = Whh + (size_t)layer*G_*256 + (size_t)n_g*256 + quad*8;
#pragma unroll
    for (int kk = 0; kk < 16; ++kk) {
      const float* src = (kk < 8) ? (wihr + kk*32) : (whhr + (kk-8)*32);
      f32x4 w0 = *(const f32x4*)src;
      f32x4 w1 = *(const f32x4*)(src+4);
      half8 hv;
      hv[0]=(_Float16)w0[0]; hv[1]=(_Float16)w0[1]; hv[2]=(_Float16)w0[2]; hv[3]=(_Float16)w0[3];
      hv[4]=(_Float16)w1[0]; hv[5]=(_Float16)w1[1]; hv[6]=(_Float16)w1[2]; hv[7]=(_Float16)w1[3];
      bf[q][kk] = hv;
    }
  }

  float bias[4];
#pragma unroll
  for (int q = 0; q < 4; ++q) {
    const int n_g = q*256 + c0 + lq;
    bias[q] = bih[layer*G_ + n_g] + bhh[layer*G_ + n_g];
  }

  f32x4 cst;
#pragma unroll
  for (int r = 0; r < 4; ++r) {
    const int b = m*16 + quad*4 + r;
    cst[r] = enc_c[b*(2*H_) + dir*H_ + c0 + lq];
  }

  u64* chOwn       = hbufT + (size_t)chain*CHAINU;
  const u64* chL0  = hbufT + (size_t)(dir*2)*CHAINU;
  int* cntOwn = flags + (size_t)(chain*2 + m)*16;
  int* cntL1  = flags + (size_t)((dir*2+1)*2 + m)*16;  // used by L0 only

  const int arow = m*16 + lq;
  const float* xrowBase = x + (size_t)arow*S_*D_;

  bool dead = false;

  for (int t = 0; t < S_; ++t) {
    f32x4 acc0 = {bias[0],bias[0],bias[0],bias[0]};
    f32x4 acc1 = {bias[1],bias[1],bias[1],bias[1]};
    f32x4 acc2 = {bias[2],bias[2],bias[2],bias[2]};
    f32x4 acc3 = {bias[3],bias[3],bias[3],bias[3]};

    if (layer == 0) {
      // x part: independent of recurrence — load, convert, MFMA before any wait
      const float* xr = xrowBase + (size_t)t*D_;
      half8 ain[8];
#pragma unroll
      for (int kk = 0; kk < 8; ++kk) {
        const int k = kk*32 + quad*8;
        half8 hv;
        if (dir == 0) {
          f32x4 a0 = *(const f32x4*)(xr + k);
          f32x4 a1 = *(const f32x4*)(xr + k + 4);
          hv[0]=(_Float16)a0[0]; hv[1]=(_Float16)a0[1]; hv[2]=(_Float16)a0[2]; hv[3]=(_Float16)a0[3];
          hv[4]=(_Float16)a1[0]; hv[5]=(_Float16)a1[1]; hv[6]=(_Float16)a1[2]; hv[7]=(_Float16)a1[3];
        } else {
          const float* p = xr + (248 - k);
          f32x4 a0 = *(const f32x4*)p;
          f32x4 a1 = *(const f32x4*)(p + 4);
          hv[0]=(_Float16)a1[3]; hv[1]=(_Float16)a1[2]; hv[2]=(_Float16)a1[1]; hv[3]=(_Float16)a1[0];
          hv[4]=(_Float16)a0[3]; hv[5]=(_Float16)a0[2]; hv[6]=(_Float16)a0[1]; hv[7]=(_Float16)a0[0];
        }
        ain[kk] = hv;
      }
#pragma unroll
      for (int kk = 0; kk < 8; ++kk) {
        acc0 = __builtin_amdgcn_mfma_f32_16x16x32_f16(ain[kk], bf[0][kk], acc0, 0,0,0);
        acc1 = __builtin_amdgcn_mfma_f32_16x16x32_f16(ain[kk], bf[1][kk], acc1, 0,0,0);
        acc2 = __builtin_amdgcn_mfma_f32_16x16x32_f16(ain[kk], bf[2][kk], acc2, 0,0,0);
        acc3 = __builtin_amdgcn_mfma_f32_16x16x32_f16(ain[kk], bf[3][kk], acc3, 0,0,0);
      }
    }

    // ---- slot-reuse gate (7-tick slack; rarely spins; same-addr broadcast) ----
    if (t >= 7) {
      const int tgtOwn = 16*(t-6);
      const int tgtOth = 16*(t-7);
      int guard = 0;
      while (true) {
        int a = __hip_atomic_load(cntOwn, __ATOMIC_RELAXED, __HIP_MEMORY_SCOPE_SYSTEM);
        bool ok = (a >= tgtOwn);
        if (layer == 0) {
          int b2 = __hip_atomic_load(cntL1, __ATOMIC_RELAXED, __HIP_MEMORY_SCOPE_SYSTEM);
          ok = ok && (b2 >= tgtOth);
        }
        if (ok) break;
        if (++guard > (1 << 20)) { dead = true; break; }
      }
    }
    if (dead) break;

    // ---- self-tagged data poll + dependent MFMAs ----
    if (layer == 0) {
      const u64* sp = chOwn + (size_t)(t & 7)*SLOTU + (size_t)arow*ROWU;
      u64 v[32];
      const unsigned tag = (unsigned)t;
      int guard = 0;
      while (true) {
        unsigned ok = 1;
#pragma unroll
        for (int kk = 0; kk < 8; ++kk) {
          const u64* p = sp + quad*4 + kk*16;
#pragma unroll
          for (int j = 0; j < 4; ++j)
            v[kk*4+j] = __hip_atomic_load(p + j, __ATOMIC_RELAXED, __HIP_MEMORY_SCOPE_SYSTEM);
        }
#pragma unroll
        for (int i2 = 0; i2 < 32; ++i2) ok &= (unsigned)((unsigned)(v[i2] >> 32) == tag);
        if (__all(ok)) break;
        if (++guard > (1 << 20)) { dead = true; break; }
      }
      if (dead) break;
#pragma unroll
      for (int kk = 0; kk < 8; ++kk) {
        H8U uu;
#pragma unroll
        for (int j = 0; j < 4; ++j) uu.d[j] = (unsigned)v[kk*4+j];
        half8 ar = uu.h;
        acc0 = __builtin_amdgcn_mfma_f32_16x16x32_f16(ar, bf[0][kk+8], acc0, 0,0,0);
        acc1 = __builtin_amdgcn_mfma_f32_16x16x32_f16(ar, bf[1][kk+8], acc1, 0,0,0);
        acc2 = __builtin_amdgcn_mfma_f32_16x16x32_f16(ar, bf[2][kk+8], acc2, 0,0,0);
        acc3 = __builtin_amdgcn_mfma_f32_16x16x32_f16(ar, bf[3][kk+8], acc3, 0,0,0);
      }
    } else {
      const u64* spI = chL0  + (size_t)((t+1) & 7)*SLOTU + (size_t)arow*ROWU;
      const u64* spR = chOwn + (size_t)(t & 7)*SLOTU + (size_t)arow*ROWU;
      u64 va[32], vr[32];
      const unsigned tagI = (unsigned)(t+1), tagR = (unsigned)t;
      int guard = 0;
      while (true) {
        unsigned ok = 1;
#pragma unroll
        for (int kk = 0; kk < 8; ++kk) {
          const u64* pI = spI + quad*4 + kk*16;
          const u64* pR = spR + quad*4 + kk*16;
#pragma unroll
          for (int j = 0; j < 4; ++j) {
            va[kk*4+j] = __hip_atomic_load(pI + j, __ATOMIC_RELAXED, __HIP_MEMORY_SCOPE_SYSTEM);
            vr[kk*4+j] = __hip_atomic_load(pR + j, __ATOMIC_RELAXED, __HIP_MEMORY_SCOPE_SYSTEM);
          }
        }
#pragma unroll
        for (int i2 = 0; i2 < 32; ++i2) {
          ok &= (unsigned)((unsigned)(va[i2] >> 32) == tagI);
          ok &= (unsigned)((unsigned)(vr[i2] >> 32) == tagR);
        }
        if (__all(ok)) break;
        if (++guard > (1 << 20)) { dead = true; break; }
      }
      if (dead) break;
#pragma unroll
      for (int kk = 0; kk < 8; ++kk) {
        H8U ua, ur;
#pragma unroll
        for (int j = 0; j < 4; ++j) { ua.d[j] = (unsigned)va[kk*4+j]; ur.d[j] = (unsigned)vr[kk*4+j]; }
        half8 ai = ua.h, ar = ur.h;
        acc0 = __builtin_amdgcn_mfma_f32_16x16x32_f16(ai, bf[0][kk], acc0, 0,0,0);
        acc1 = __builtin_amdgcn_mfma_f32_16x16x32_f16(ai, bf[1][kk], acc1, 0,0,0);
        acc2 = __builtin_amdgcn_mfma_f32_16x16x32_f16(ai, bf[2][kk], acc2, 0,0,0);
        acc3 = __builtin_amdgcn_mfma_f32_16x16x32_f16(ai, bf[3][kk], acc3, 0,0,0);
        acc0 = __builtin_amdgcn_mfma_f32_16x16x32_f16(ar, bf[0][kk+8], acc0, 0,0,0);
        acc1 = __builtin_amdgcn_mfma_f32_16x16x32_f16(ar, bf[1][kk+8], acc1, 0,0,0);
        acc2 = __builtin_amdgcn_mfma_f32_16x16x32_f16(ar, bf[2][kk+8], acc2, 0,0,0);
        acc3 = __builtin_amdgcn_mfma_f32_16x16x32_f16(ar, bf[3][kk+8], acc3, 0,0,0);
      }
    }

    // LSTM elementwise (in-register)
    float hval[4];
#pragma unroll
    for (int r = 0; r < 4; ++r) {
      float si = sigmoidf_(acc0[r]);
      float sf = sigmoidf_(acc1[r]);
      float tg = tanhf_  (acc2[r]);
      float so = sigmoidf_(acc3[r]);
      float cn = sf*cst[r] + si*tg;
      cst[r] = cn;
      hval[r] = so*tanhf_(cn);
    }

    // publish: tagged u64 stores to slot (t+1)&7, tag t+1 — no drain needed
    // before consumers can use them (tags self-validate)
    u64* wp = chOwn + (size_t)((t+1) & 7)*SLOTU + (c0 >> 1);
    const u64 tagHi = ((u64)(unsigned)(t+1)) << 32;
#pragma unroll
    for (int r = 0; r < 4; ++r) {
      float partner = __shfl_xor(hval[r], 1);
      if (!(lq & 1)) {
        unsigned lo = (unsigned)__builtin_bit_cast(unsigned short, (_Float16)hval[r])
                    | ((unsigned)__builtin_bit_cast(unsigned short, (_Float16)partner) << 16);
        const int b = m*16 + quad*4 + r;
        __hip_atomic_store(wp + (size_t)b*ROWU + (lq >> 1), tagHi | lo,
                           __ATOMIC_RELAXED, __HIP_MEMORY_SCOPE_SYSTEM);
      }
    }

    // completion counter (backpressure only; after loads+stores drained)
    asm volatile("s_waitcnt vmcnt(0)" ::: "memory");
    if (lane == 0)
      __hip_atomic_fetch_add(cntOwn, 1, __ATOMIC_RELAXED, __HIP_MEMORY_SCOPE_SYSTEM);

    // out[] stores off the critical path
    if (layer == 1) {
      const int colg = dir*256 + c0 + lq;
#pragma unroll
      for (int r = 0; r < 4; ++r) {
        const int b = m*16 + quad*4 + r;
        out[((size_t)b*S_ + t)*(2*H_) + colg] = hval[r];
      }
      if (t == S_-1) {
#pragma unroll
        for (int r = 0; r < 4; ++r) {
          const int b = m*16 + quad*4 + r;
          out[OUT0 + (size_t)b*(2*H_) + colg] = hval[r];
          out[OUT0 + B_*2*H_ + (size_t)b*(2*H_) + colg] = cst[r];
        }
      }
    }
  }
}

extern "C" void kernel_launch(void* const* d_in, const int* in_sizes, int n_in,
                              void* d_out, int out_size, void* d_ws, size_t ws_size,
                              hipStream_t stream) {
  const float* x     = (const float*)d_in[0];
  const float* enc_h = (const float*)d_in[1];
  const float* enc_c = (const float*)d_in[2];
  const float* Wih_f = (const float*)d_in[3];
  const float* Whh_f = (const float*)d_in[4];
  const float* bih_f = (const float*)d_in[5];
  const float* bhh_f = (const float*)d_in[6];
  const float* Wih_b = (const float*)d_in[7];
  const float* Whh_b = (const float*)d_in[8];
  const float* bih_b = (const float*)d_in[9];
  const float* bhh_b = (const float*)d_in[10];

  int* flags  = (int*)d_ws;
  u64* hbufT  = (u64*)((char*)d_ws + 8192);

  lstm_prep<<<64, 256, 0, stream>>>(enc_h, flags, hbufT);
  lstm_main<<<128, 64, 0, stream>>>(x, enc_c, Wih_f, Whh_f, bih_f, bhh_f,
                                    Wih_b, Whh_b, bih_b, bhh_b,
                                    (float*)d_out, flags, hbufT);
}